// Round 1
// baseline (835.347 us; speedup 1.0000x reference)
//
#include <hip/hip_runtime.h>
#include <hip/hip_bf16.h>

// GraphSAGE edge classifier, fp32.
// Pipeline:
//  K1 degree      : cnt[dst]++ (int atomics)
//  K2 scan        : row = exclusive_scan(cnt), cursor = row (single block)
//  K3 build       : CSR srclist via cursor atomics
//  K4 lin1        : y = x@W1l, z = x@W1r   (LDS-tiled, 32 nodes/block)
//  K5 agg1        : h1 = relu(mean_agg(y) + b1 + z); p = h1@W2l; q = h1@W2r
//  K6 agg2        : h2 = relu(mean_agg(p) + b2 + q); u = h2@Wc[:16]; v = h2@Wc[16:]
//  K7 edge_out    : out = log_softmax(u[src] + v[dst] + bc)

__global__ __launch_bounds__(256) void degree_kernel(const int* __restrict__ ei,
                                                     int* __restrict__ cnt, int E) {
  int e = blockIdx.x * 256 + threadIdx.x;
  if (e < E) atomicAdd(&cnt[ei[E + e]], 1);
}

#define SCAN_T 1024
#define SCAN_I 16
__global__ __launch_bounds__(SCAN_T) void scan_kernel(const int* __restrict__ cnt,
                                                      int* __restrict__ row,
                                                      int* __restrict__ cursor, int n) {
  __shared__ int wsum[SCAN_T / 64];
  int lane = threadIdx.x & 63;
  int wid = threadIdx.x >> 6;
  int running = 0;
  for (int base = 0; base < n; base += SCAN_T * SCAN_I) {
    int idx0 = base + threadIdx.x * SCAN_I;
    int v[SCAN_I];
    int tsum = 0;
#pragma unroll
    for (int i = 0; i < SCAN_I; ++i) {
      int ii = idx0 + i;
      v[i] = (ii < n) ? cnt[ii] : 0;
      tsum += v[i];
    }
    // inclusive wave scan of per-thread sums
    int incl = tsum;
#pragma unroll
    for (int d = 1; d < 64; d <<= 1) {
      int t = __shfl_up(incl, d);
      if (lane >= d) incl += t;
    }
    if (lane == 63) wsum[wid] = incl;
    __syncthreads();
    if (wid == 0 && lane < (SCAN_T / 64)) {
      int w = wsum[lane];
#pragma unroll
      for (int d = 1; d < (SCAN_T / 64); d <<= 1) {
        int t = __shfl_up(w, d);
        if (lane >= d) w += t;
      }
      wsum[lane] = w;
    }
    __syncthreads();
    int offset = running + (wid ? wsum[wid - 1] : 0) + (incl - tsum);
#pragma unroll
    for (int i = 0; i < SCAN_I; ++i) {
      int ii = idx0 + i;
      if (ii < n) { row[ii] = offset; cursor[ii] = offset; }
      offset += v[i];
    }
    running += wsum[(SCAN_T / 64) - 1];
    __syncthreads();
  }
  if (threadIdx.x == 0) row[n] = running;
}

__global__ __launch_bounds__(256) void build_kernel(const int* __restrict__ ei,
                                                    int* __restrict__ cursor,
                                                    int* __restrict__ srclist, int E) {
  int e = blockIdx.x * 256 + threadIdx.x;
  if (e < E) {
    int src = ei[e];
    int dst = ei[E + e];
    int pos = atomicAdd(&cursor[dst], 1);
    srclist[pos] = src;
  }
}

// y = x@W1l, z = x@W1r ; 32 nodes per 256-thread block
__global__ __launch_bounds__(256) void lin1_kernel(const float* __restrict__ x,
                                                   const float* __restrict__ W1l,
                                                   const float* __restrict__ W1r,
                                                   float* __restrict__ y,
                                                   float* __restrict__ z, int N) {
  __shared__ float Xs[32 * 129];   // row stride 129 -> conflict-free column reads
  __shared__ float Ws[128 * 32];   // [k][c]: c<16 -> W1l, c>=16 -> W1r
  int t = threadIdx.x;
  for (int i = t; i < 128 * 16; i += 256) {
    int k = i >> 4, c = i & 15;
    Ws[k * 32 + c] = W1l[i];
    Ws[k * 32 + 16 + c] = W1r[i];
  }
  int nb = blockIdx.x * 32;
  const float4* xg = (const float4*)(x + (size_t)nb * 128);
  for (int i4 = t; i4 < 32 * 32; i4 += 256) {  // 1024 float4 = 32 rows x 128
    float4 val = xg[i4];
    int r = i4 >> 5, c4 = (i4 & 31) * 4;
    float* dp = &Xs[r * 129 + c4];
    dp[0] = val.x; dp[1] = val.y; dp[2] = val.z; dp[3] = val.w;
  }
  __syncthreads();
  int n = t & 31, cg = t >> 5;  // node-in-tile, col-group (4 cols each)
  float a0 = 0.f, a1 = 0.f, a2 = 0.f, a3 = 0.f;
  for (int k = 0; k < 128; ++k) {
    float xv = Xs[n * 129 + k];
    const float* wr = &Ws[k * 32 + cg * 4];
    a0 += xv * wr[0]; a1 += xv * wr[1]; a2 += xv * wr[2]; a3 += xv * wr[3];
  }
  int node = nb + n;
  if (node < N) {
    int c = cg * 4;
    float* op = (c < 16) ? (y + (size_t)node * 16 + c)
                         : (z + (size_t)node * 16 + (c - 16));
    op[0] = a0; op[1] = a1; op[2] = a2; op[3] = a3;
  }
}

// mean-agg(y) -> h1 = relu(+b1+z) -> p = h1@W2l, q = h1@W2r ; 16 lanes/node
__global__ __launch_bounds__(256) void agg1_kernel(const float* __restrict__ y,
                                                   const float* __restrict__ z,
                                                   const int* __restrict__ row,
                                                   const int* __restrict__ srclist,
                                                   const float* __restrict__ b1,
                                                   const float* __restrict__ W2l,
                                                   const float* __restrict__ W2r,
                                                   float* __restrict__ p,
                                                   float* __restrict__ q, int N) {
  int g = (blockIdx.x * 256 + threadIdx.x) >> 4;
  int k = threadIdx.x & 15;
  if (g >= N) return;
  int beg = row[g], end = row[g + 1];
  float acc = 0.f;
  for (int j = beg; j < end; ++j) {
    int s = srclist[j];
    acc += y[(size_t)s * 16 + k];
  }
  int deg = end - beg;
  float agg = acc / (float)(deg > 0 ? deg : 1);
  float h = agg + b1[k] + z[(size_t)g * 16 + k];
  h = fmaxf(h, 0.f);
  float pa = 0.f, qa = 0.f;
#pragma unroll
  for (int kk = 0; kk < 16; ++kk) {
    float hk = __shfl(h, kk, 16);
    pa += hk * W2l[kk * 16 + k];
    qa += hk * W2r[kk * 16 + k];
  }
  p[(size_t)g * 16 + k] = pa;
  q[(size_t)g * 16 + k] = qa;
}

// mean-agg(p) -> h2 = relu(+b2+q) -> u = h2@Wc[:16], v = h2@Wc[16:]
__global__ __launch_bounds__(256) void agg2_kernel(const float* __restrict__ p,
                                                   const float* __restrict__ q,
                                                   const int* __restrict__ row,
                                                   const int* __restrict__ srclist,
                                                   const float* __restrict__ b2,
                                                   const float* __restrict__ Wc,
                                                   float* __restrict__ U,
                                                   float* __restrict__ V, int N) {
  int g = (blockIdx.x * 256 + threadIdx.x) >> 4;
  int k = threadIdx.x & 15;
  if (g >= N) return;
  int beg = row[g], end = row[g + 1];
  float acc = 0.f;
  for (int j = beg; j < end; ++j) {
    int s = srclist[j];
    acc += p[(size_t)s * 16 + k];
  }
  int deg = end - beg;
  float agg = acc / (float)(deg > 0 ? deg : 1);
  float h = agg + b2[k] + q[(size_t)g * 16 + k];
  h = fmaxf(h, 0.f);
  int wbase = (k < 8) ? 0 : 16;  // u-path rows 0..15, v-path rows 16..31
  int c = k & 7;
  float o = 0.f;
#pragma unroll
  for (int kk = 0; kk < 16; ++kk) {
    float hk = __shfl(h, kk, 16);
    o += hk * Wc[(wbase + kk) * 8 + c];
  }
  if (k < 8) U[(size_t)g * 8 + c] = o;
  else       V[(size_t)g * 8 + c] = o;
}

__global__ __launch_bounds__(256) void edge_out_kernel(const int* __restrict__ ei,
                                                       const float* __restrict__ U,
                                                       const float* __restrict__ V,
                                                       const float* __restrict__ bc,
                                                       float* __restrict__ out, int E) {
  int e = blockIdx.x * 256 + threadIdx.x;
  if (e >= E) return;
  int src = ei[e];
  int dst = ei[E + e];
  const float4* up = (const float4*)(U + (size_t)src * 8);
  const float4* vp = (const float4*)(V + (size_t)dst * 8);
  float4 a0 = up[0], a1 = up[1];
  float4 b0 = vp[0], b1 = vp[1];
  float4 c0 = ((const float4*)bc)[0], c1 = ((const float4*)bc)[1];
  float t[8];
  t[0] = a0.x + b0.x + c0.x; t[1] = a0.y + b0.y + c0.y;
  t[2] = a0.z + b0.z + c0.z; t[3] = a0.w + b0.w + c0.w;
  t[4] = a1.x + b1.x + c1.x; t[5] = a1.y + b1.y + c1.y;
  t[6] = a1.z + b1.z + c1.z; t[7] = a1.w + b1.w + c1.w;
  float m = t[0];
#pragma unroll
  for (int c = 1; c < 8; ++c) m = fmaxf(m, t[c]);
  float s = 0.f;
#pragma unroll
  for (int c = 0; c < 8; ++c) s += __expf(t[c] - m);
  float lse = m + __logf(s);
  float4 o0 = make_float4(t[0] - lse, t[1] - lse, t[2] - lse, t[3] - lse);
  float4 o1 = make_float4(t[4] - lse, t[5] - lse, t[6] - lse, t[7] - lse);
  float4* op = (float4*)(out + (size_t)e * 8);
  op[0] = o0; op[1] = o1;
}

extern "C" void kernel_launch(void* const* d_in, const int* in_sizes, int n_in,
                              void* d_out, int out_size, void* d_ws, size_t ws_size,
                              hipStream_t stream) {
  const float* x   = (const float*)d_in[0];
  const int*   ei  = (const int*)d_in[1];
  const float* W1l = (const float*)d_in[2];
  const float* b1  = (const float*)d_in[3];
  const float* W1r = (const float*)d_in[4];
  const float* W2l = (const float*)d_in[5];
  const float* b2  = (const float*)d_in[6];
  const float* W2r = (const float*)d_in[7];
  const float* Wc  = (const float*)d_in[8];
  const float* bc  = (const float*)d_in[9];
  float* out = (float*)d_out;

  const int N = in_sizes[0] / 128;   // 100000
  const int E = in_sizes[1] / 2;     // 3200000
  const size_t N16 = (size_t)N * 16;

  // Workspace layout (floats then ints)
  float* A = (float*)d_ws;           // y, later u (N*8)
  float* B = A + N16;                // z, later v (N*8)
  float* C = B + N16;                // p
  float* D = C + N16;                // q
  int* cnt     = (int*)(D + N16);    // N
  int* row     = cnt + N;            // N+1
  int* cursor  = row + (N + 1);      // N
  int* srclist = cursor + N;         // E

  hipMemsetAsync(cnt, 0, (size_t)N * sizeof(int), stream);

  int egrid = (E + 255) / 256;
  degree_kernel<<<egrid, 256, 0, stream>>>(ei, cnt, E);
  scan_kernel<<<1, SCAN_T, 0, stream>>>(cnt, row, cursor, N);
  build_kernel<<<egrid, 256, 0, stream>>>(ei, cursor, srclist, E);

  lin1_kernel<<<(N + 31) / 32, 256, 0, stream>>>(x, W1l, W1r, A, B, N);

  int ngrid = (N * 16 + 255) / 256;
  agg1_kernel<<<ngrid, 256, 0, stream>>>(A, B, row, srclist, b1, W2l, W2r, C, D, N);
  agg2_kernel<<<ngrid, 256, 0, stream>>>(C, D, row, srclist, b2, Wc, A, B, N);

  edge_out_kernel<<<egrid, 256, 0, stream>>>(ei, A, B, bc, out, E);
}